// Round 1
// baseline (878.247 us; speedup 1.0000x reference)
//
#include <hip/hip_runtime.h>
#include <hip/hip_bf16.h>
#include <math.h>

#define NTOK 8192
#define DIM  768
#define HDIM 3072
#define NE   8
#define CAP  2560
#define AMAX 16384

typedef __bf16 bf16x8  __attribute__((ext_vector_type(8)));
typedef __bf16 bf16x2  __attribute__((ext_vector_type(2)));
typedef float  floatx4 __attribute__((ext_vector_type(4)));

typedef unsigned int u32_g __attribute__((address_space(1)));
typedef unsigned int u32_l __attribute__((address_space(3)));

__device__ __forceinline__ void gl_lds16(const void* g, void* l) {
  // 16B per lane, LDS dest = wave-uniform base + lane*16
  __builtin_amdgcn_global_load_lds((const u32_g*)g, (u32_l*)l, 16, 0, 0);
}

// ---------------- weight transpose + fp32->bf16 convert: src[E][K][N] -> dst[E][N][K] ----
__global__ __launch_bounds__(256) void transpose_conv(
    const float* __restrict__ src, __bf16* __restrict__ dst, int Kd, int Nd)
{
  const int e = blockIdx.y;
  const int tilesK = Kd >> 6;
  const int bk = blockIdx.x % tilesK, bn = blockIdx.x / tilesK;
  __shared__ float T[64][65];
  const float* se = src + (size_t)e * Kd * Nd;
  const int k0 = bk * 64, n0 = bn * 64;
  const int tid = threadIdx.x;
#pragma unroll
  for (int it = 0; it < 16; ++it) {
    int flat = tid + it * 256;
    int kk = flat >> 6, nn = flat & 63;
    T[kk][nn] = se[(size_t)(k0 + kk) * Nd + n0 + nn];
  }
  __syncthreads();
  const int n = tid >> 2, kg = tid & 3;
  bf16x8 v0, v1;
#pragma unroll
  for (int q = 0; q < 8; ++q) v0[q] = (__bf16)T[kg * 16 + q][n];
#pragma unroll
  for (int q = 0; q < 8; ++q) v1[q] = (__bf16)T[kg * 16 + 8 + q][n];
  __bf16* de = dst + (size_t)e * Nd * Kd + (size_t)(n0 + n) * Kd + k0 + kg * 16;
  *(bf16x8*)(de) = v0;
  *(bf16x8*)(de + 8) = v1;
}

// ---------------- router: logits, softmax, top-2, aux stats, assignment lists ----------
__global__ __launch_bounds__(256) void router_kernel(
    const float* __restrict__ x, const float* __restrict__ rw,
    int* __restrict__ list_len, double* __restrict__ imp, double* __restrict__ loadacc,
    int* __restrict__ aidx, float* __restrict__ keyarr, float* __restrict__ warr)
{
  __shared__ float Wl[NE * DIM];   // Wl[e*DIM+d] = rw[d*NE+e]
  const int tid = threadIdx.x;
  for (int i = tid; i < NE * DIM; i += 256) {
    int e = i / DIM, d = i - e * DIM;
    Wl[i] = rw[d * NE + e];
  }
  __syncthreads();
  const int wave = tid >> 6, lane = tid & 63;
  double my_imp = 0.0, my_load = 0.0;

  for (int it = 0; it < 8; ++it) {
    const int n = blockIdx.x * 32 + wave * 8 + it;
    const float* xr = x + (size_t)n * DIM;
    float part[NE];
#pragma unroll
    for (int e = 0; e < NE; ++e) part[e] = 0.f;
#pragma unroll
    for (int c = 0; c < DIM / 64; ++c) {
      float xv = xr[c * 64 + lane];
#pragma unroll
      for (int e = 0; e < NE; ++e) part[e] += xv * Wl[e * DIM + c * 64 + lane];
    }
#pragma unroll
    for (int off = 32; off > 0; off >>= 1) {
#pragma unroll
      for (int e = 0; e < NE; ++e) part[e] += __shfl_xor(part[e], off);
    }
    // top-2, ties -> lower index (lax.top_k semantics)
    int e0 = 0; float v0 = part[0];
#pragma unroll
    for (int e = 1; e < NE; ++e) if (part[e] > v0) { v0 = part[e]; e0 = e; }
    int e1 = -1; float v1 = -3.4e38f;
#pragma unroll
    for (int e = 0; e < NE; ++e) if (e != e0 && part[e] > v1) { v1 = part[e]; e1 = e; }

    float pexp[NE]; float s = 0.f;
#pragma unroll
    for (int e = 0; e < NE; ++e) { pexp[e] = expf(part[e] - v0); s += pexp[e]; }
    const float inv = 1.0f / s;
    const float pr = inv;               // exp(0)*inv -> top-1 prob = priority
    float w1v = 0.f;
#pragma unroll
    for (int e = 0; e < NE; ++e) if (e == e1) w1v = pexp[e] * inv;

    // per-lane-expert double accumulation: lane e accumulates expert e
    float myl = 0.f, mypexp = 0.f;
#pragma unroll
    for (int e = 0; e < NE; ++e) if (lane == e) { myl = part[e]; mypexp = pexp[e]; }
    if (lane < NE) {
      my_imp  += (double)(mypexp * inv);
      // 1 - Phi((thr - logit)/NOISE_STD) = 0.5*erfc((thr-logit)/(0.125*sqrt(2)))
      my_load += (double)(0.5f * erfcf((v1 - myl) * 5.656854249492380f));
    }
    if (lane == 0) {
      int p0 = atomicAdd(&list_len[e0], 1);
      int p1 = atomicAdd(&list_len[e1], 1);
      aidx[e0 * AMAX + p0]   = n * 2;
      keyarr[e0 * AMAX + p0] = (float)(e0 * 4) - pr;            // e*(K+2) - score, fp32 like ref
      warr[e0 * AMAX + p0]   = pr;
      aidx[e1 * AMAX + p1]   = n * 2 + 1;
      keyarr[e1 * AMAX + p1] = (float)(e1 * 4) - (pr - 1.0f);
      warr[e1 * AMAX + p1]   = w1v;
    }
  }
  if (lane < NE) {
    unsafeAtomicAdd(&imp[lane], my_imp);
    unsafeAtomicAdd(&loadacc[lane], my_load);
  }
}

// ---------------- capacity keep/compact + scalar outputs -------------------------------
__global__ __launch_bounds__(256) void compact_kernel(
    const int* __restrict__ list_len, const int* __restrict__ aidx,
    const float* __restrict__ keyarr, const float* __restrict__ warr,
    int* __restrict__ dtok, float* __restrict__ dw,
    const double* __restrict__ imp, const double* __restrict__ loadacc,
    float* __restrict__ out_scalars)
{
  __shared__ float sk[6144];
  __shared__ int   sa[6144];
  const int e = blockIdx.x, tid = threadIdx.x;
  const int C = list_len[e];
  if (C <= CAP) {
    // nothing dropped for this expert: keep-set = all, slot order is free
    for (int t = tid; t < C; t += 256) {
      int a = aidx[e * AMAX + t];
      dtok[e * CAP + t] = a >> 1;
      dw[e * CAP + t]   = warr[e * AMAX + t];
    }
  } else {
    const bool useL = (C <= 6144);
    if (useL) {
      for (int t = tid; t < C; t += 256) { sk[t] = keyarr[e*AMAX+t]; sa[t] = aidx[e*AMAX+t]; }
      __syncthreads();
    }
    for (int t = tid; t < C; t += 256) {
      float kt = keyarr[e*AMAX+t]; int at = aidx[e*AMAX+t];
      int r = 0;
      for (int u = 0; u < C; ++u) {
        float ku = useL ? sk[u] : keyarr[e*AMAX+u];
        int   au = useL ? sa[u] : aidx[e*AMAX+u];
        if (ku < kt || (ku == kt && au < at)) ++r;   // stable by assignment index
      }
      if (r < CAP) { dtok[e*CAP + r] = at >> 1; dw[e*CAP + r] = warr[e*AMAX+t]; }
    }
  }
  if (e == 0 && tid == 0) {
    double mi = 0, ml = 0;
    for (int i = 0; i < NE; ++i) { mi += imp[i]; ml += loadacc[i]; }
    mi /= NE; ml /= NE;
    double vi = 0, vl = 0;
    for (int i = 0; i < NE; ++i) {
      double di = imp[i] - mi;     vi += di * di;
      double dl = loadacc[i] - ml; vl += dl * dl;
    }
    vi /= NE; vl /= NE;
    double li = vi / (mi * mi + 1e-6), ll = vl / (ml * ml + 1e-6);
    out_scalars[0] = (float)(0.5 * (li + ll));     // aux_loss
    int drop = 0;
    for (int i = 0; i < NE; ++i) { int c2 = list_len[i]; if (c2 > CAP) drop += c2 - CAP; }
    out_scalars[1] = (float)drop;                  // dropped
    for (int i = 0; i < NE; ++i) out_scalars[2 + i] = (float)list_len[i];  // expert_counts
  }
}

// ---------------- gather kept rows into padded bf16 A buffer [E][CAP][DIM] -------------
__global__ __launch_bounds__(256) void gather_kernel(
    const float* __restrict__ x, const int* __restrict__ dtok,
    const int* __restrict__ list_len, __bf16* __restrict__ Ag)
{
  const int row  = blockIdx.x * 4 + (threadIdx.x >> 6);
  const int lane = threadIdx.x & 63;
  const int e = row / CAP, slot = row - e * CAP;
  const int kept = min(list_len[e], CAP);
  __bf16* dst = Ag + (size_t)row * DIM;
  if (slot < kept) {
    const float* srcr = x + (size_t)dtok[e * CAP + slot] * DIM;
#pragma unroll
    for (int c = 0; c < DIM / 128; ++c) {
      float2 v = *(const float2*)(srcr + c * 128 + lane * 2);
      bf16x2 o; o[0] = (__bf16)v.x; o[1] = (__bf16)v.y;
      *(bf16x2*)(dst + c * 128 + lane * 2) = o;
    }
  } else {
    bf16x2 z; z[0] = (__bf16)0.f; z[1] = (__bf16)0.f;
#pragma unroll
    for (int c = 0; c < DIM / 128; ++c) *(bf16x2*)(dst + c * 128 + lane * 2) = z;
  }
}

// ---------------- grouped GEMM: C[M,N] = A[M,K] * BT[N,K]^T, m97-style -----------------
// MODE 0: h = gelu_exact(A*B + bias), store bf16.   MODE 1: atomic scatter w*(A*B+bias).
template<int MODE>
__global__ __launch_bounds__(256) void moe_gemm(
    const __bf16* __restrict__ Aall, const __bf16* __restrict__ BTall,
    const float* __restrict__ bias, __bf16* __restrict__ Hout,
    float* __restrict__ Out, const int* __restrict__ dtok, const float* __restrict__ dww,
    const int* __restrict__ list_len, int Kd, int Nd, int tilesM)
{
  const int e = blockIdx.y;
  const int kept = min(list_len[e], CAP);
  const int tm = blockIdx.x % tilesM, tn = blockIdx.x / tilesM;
  const int mUsed = (kept + 127) >> 7;
  if (tm >= mUsed) return;

  __shared__ __bf16 As[8 * 64 * 8];   // [group g][lane][8] : A[m0+g*16+(l&15)][k0+(l>>4)*8+j]
  __shared__ __bf16 Bs[8 * 64 * 8];   // same structure over the 128 n-columns (BT rows)

  const int tid = threadIdx.x, lane = tid & 63, wave = tid >> 6;
  const int wm = wave & 1, wn = wave >> 1;
  const int m0 = tm * 128, n0 = tn * 128;

  const __bf16* Ae = Aall + (size_t)e * CAP * Kd;
  const __bf16* Be = BTall + (size_t)e * Nd * Kd;

  const int lr = lane & 15, lc = (lane >> 4) * 8;
  const __bf16* pA0 = Ae + (size_t)(m0 + (wave * 2 + 0) * 16 + lr) * Kd + lc;
  const __bf16* pA1 = Ae + (size_t)(m0 + (wave * 2 + 1) * 16 + lr) * Kd + lc;
  const __bf16* pB0 = Be + (size_t)(n0 + (wave * 2 + 0) * 16 + lr) * Kd + lc;
  const __bf16* pB1 = Be + (size_t)(n0 + (wave * 2 + 1) * 16 + lr) * Kd + lc;
  __bf16* lA0 = &As[(wave * 2 + 0) * 512];
  __bf16* lA1 = &As[(wave * 2 + 1) * 512];
  __bf16* lB0 = &Bs[(wave * 2 + 0) * 512];
  __bf16* lB1 = &Bs[(wave * 2 + 1) * 512];

  floatx4 acc[4][4];
#pragma unroll
  for (int i = 0; i < 4; ++i)
#pragma unroll
    for (int j = 0; j < 4; ++j) acc[i][j] = (floatx4)0.f;

  const int kIters = Kd >> 5;
  for (int kt = 0; kt < kIters; ++kt) {
    gl_lds16(pA0, lA0); gl_lds16(pA1, lA1);
    gl_lds16(pB0, lB0); gl_lds16(pB1, lB1);
    pA0 += 32; pA1 += 32; pB0 += 32; pB1 += 32;
    __syncthreads();                       // drains vmcnt before ds_read
    bf16x8 af[4], bfr[4];
#pragma unroll
    for (int i = 0; i < 4; ++i) af[i]  = *(const bf16x8*)(&As[((wm * 4 + i) * 64 + lane) * 8]);
#pragma unroll
    for (int j = 0; j < 4; ++j) bfr[j] = *(const bf16x8*)(&Bs[((wn * 4 + j) * 64 + lane) * 8]);
#pragma unroll
    for (int i = 0; i < 4; ++i)
#pragma unroll
      for (int j = 0; j < 4; ++j)
        acc[i][j] = __builtin_amdgcn_mfma_f32_16x16x32_bf16(af[i], bfr[j], acc[i][j], 0, 0, 0);
    __syncthreads();
  }

  const int quad = lane >> 4, lcol = lane & 15;
  float bcol[4];
#pragma unroll
  for (int j = 0; j < 4; ++j) bcol[j] = bias[e * Nd + n0 + wn * 64 + j * 16 + lcol];

  if (MODE == 0) {
#pragma unroll
    for (int i = 0; i < 4; ++i) {
#pragma unroll
      for (int r = 0; r < 4; ++r) {
        const int row = m0 + wm * 64 + i * 16 + quad * 4 + r;  // C/D: row=(l>>4)*4+reg, col=l&15
        __bf16* hrow = Hout + ((size_t)(e * CAP + row)) * Nd;
#pragma unroll
        for (int j = 0; j < 4; ++j) {
          float v = acc[i][j][r] + bcol[j];
          float g = 0.5f * v * (1.0f + erff(v * 0.7071067811865475f));
          hrow[n0 + wn * 64 + j * 16 + lcol] = (__bf16)g;
        }
      }
    }
  } else {
#pragma unroll
    for (int i = 0; i < 4; ++i) {
#pragma unroll
      for (int r = 0; r < 4; ++r) {
        const int row = m0 + wm * 64 + i * 16 + quad * 4 + r;
        const float w = dww[e * CAP + row];
        if (w != 0.0f) {
          const int tok = dtok[e * CAP + row];
          float* orow = Out + (size_t)tok * DIM;
#pragma unroll
          for (int j = 0; j < 4; ++j) {
            float v = w * (acc[i][j][r] + bcol[j]);
            unsafeAtomicAdd(&orow[n0 + wn * 64 + j * 16 + lcol], v);
          }
        }
      }
    }
  }
}

extern "C" void kernel_launch(void* const* d_in, const int* in_sizes, int n_in,
                              void* d_out, int out_size, void* d_ws, size_t ws_size,
                              hipStream_t stream) {
  (void)in_sizes; (void)n_in; (void)out_size; (void)ws_size;
  const float* x  = (const float*)d_in[0];
  const float* rw = (const float*)d_in[1];
  const float* w1 = (const float*)d_in[2];
  const float* b1 = (const float*)d_in[3];
  const float* w2 = (const float*)d_in[4];
  const float* b2 = (const float*)d_in[5];
  float* out = (float*)d_out;
  char* ws = (char*)d_ws;

  // ws layout (224 MiB total)
  int*    list_len = (int*)(ws + 0);
  double* imp      = (double*)(ws + 64);
  double* loadacc  = (double*)(ws + 128);
  int*    dtok     = (int*)(ws + 256);
  float*  dw       = (float*)(ws + 256 + 81920);
  int*    aidx     = (int*)(ws + 164096);
  float*  keyarr   = (float*)(ws + 164096 + 524288);
  float*  warr     = (float*)(ws + 164096 + 1048576);
  __bf16* W1T      = (__bf16*)(ws + 2097152);
  __bf16* W2T      = (__bf16*)(ws + 2097152 + 37748736);
  __bf16* Ag       = (__bf16*)(ws + 2097152 + 2 * 37748736);
  __bf16* hbuf     = (__bf16*)(ws + 2097152 + 2 * 37748736 + 31457280);

  hipMemsetAsync(d_out, 0, (size_t)NTOK * DIM * sizeof(float), stream);  // atomic-add target
  hipMemsetAsync(ws, 0, 164096, stream);                                 // counters + dispatch bufs

  transpose_conv<<<dim3(576, 8), 256, 0, stream>>>(w1, W1T, DIM, HDIM);
  transpose_conv<<<dim3(576, 8), 256, 0, stream>>>(w2, W2T, HDIM, DIM);
  router_kernel<<<NTOK / 32, 256, 0, stream>>>(x, rw, list_len, imp, loadacc, aidx, keyarr, warr);
  compact_kernel<<<NE, 256, 0, stream>>>(list_len, aidx, keyarr, warr, dtok, dw, imp, loadacc,
                                         out + (size_t)NTOK * DIM);
  gather_kernel<<<(NE * CAP) / 4, 256, 0, stream>>>(x, dtok, list_len, Ag);
  moe_gemm<0><<<dim3(20 * (HDIM / 128), NE), 256, 0, stream>>>(
      Ag, W1T, b1, hbuf, nullptr, nullptr, nullptr, list_len, DIM, HDIM, 20);
  moe_gemm<1><<<dim3(20 * (DIM / 128), NE), 256, 0, stream>>>(
      hbuf, W2T, b2, nullptr, out, dtok, dw, list_len, HDIM, DIM, 20);
}

// Round 2
// 835.859 us; speedup vs baseline: 1.0507x; 1.0507x over previous
//
#include <hip/hip_runtime.h>
#include <hip/hip_bf16.h>
#include <math.h>

#define NTOK 8192
#define DIM  768
#define HDIM 3072
#define NE   8
#define CAP  2560
#define AMAX 16384

typedef __bf16 bf16x8  __attribute__((ext_vector_type(8)));
typedef __bf16 bf16x2  __attribute__((ext_vector_type(2)));
typedef float  floatx4 __attribute__((ext_vector_type(4)));

typedef unsigned int u32_g __attribute__((address_space(1)));
typedef unsigned int u32_l __attribute__((address_space(3)));

__device__ __forceinline__ void gl_lds16(const void* g, void* l) {
  // 16B per lane, LDS dest = wave-uniform base + lane*16
  __builtin_amdgcn_global_load_lds((const u32_g*)g, (u32_l*)l, 16, 0, 0);
}

// ---------------- weight transpose + fp32->bf16 convert: src[E][K][N] -> dst[E][N][K] ----
__global__ __launch_bounds__(256) void transpose_conv(
    const float* __restrict__ src, __bf16* __restrict__ dst, int Kd, int Nd)
{
  const int e = blockIdx.y;
  const int tilesK = Kd >> 6;
  const int bk = blockIdx.x % tilesK, bn = blockIdx.x / tilesK;
  __shared__ float T[64][65];
  const float* se = src + (size_t)e * Kd * Nd;
  const int k0 = bk * 64, n0 = bn * 64;
  const int tid = threadIdx.x;
#pragma unroll
  for (int it = 0; it < 16; ++it) {
    int flat = tid + it * 256;
    int kk = flat >> 6, nn = flat & 63;
    T[kk][nn] = se[(size_t)(k0 + kk) * Nd + n0 + nn];
  }
  __syncthreads();
  const int n = tid >> 2, kg = tid & 3;
  bf16x8 v0, v1;
#pragma unroll
  for (int q = 0; q < 8; ++q) v0[q] = (__bf16)T[kg * 16 + q][n];
#pragma unroll
  for (int q = 0; q < 8; ++q) v1[q] = (__bf16)T[kg * 16 + 8 + q][n];
  __bf16* de = dst + (size_t)e * Nd * Kd + (size_t)(n0 + n) * Kd + k0 + kg * 16;
  *(bf16x8*)(de) = v0;
  *(bf16x8*)(de + 8) = v1;
}

// ---------------- router: logits, softmax, top-2, aux stats, assignment lists ----------
__global__ __launch_bounds__(256) void router_kernel(
    const float* __restrict__ x, const float* __restrict__ rw,
    int* __restrict__ list_len, double* __restrict__ imp, double* __restrict__ loadacc,
    int* __restrict__ aidx, float* __restrict__ keyarr, float* __restrict__ warr)
{
  __shared__ float Wl[NE * DIM];   // Wl[e*DIM+d] = rw[d*NE+e]
  const int tid = threadIdx.x;
  for (int i = tid; i < NE * DIM; i += 256) {
    int e = i / DIM, d = i - e * DIM;
    Wl[i] = rw[d * NE + e];
  }
  __syncthreads();
  const int wave = tid >> 6, lane = tid & 63;
  double my_imp = 0.0, my_load = 0.0;

  for (int it = 0; it < 8; ++it) {
    const int n = blockIdx.x * 32 + wave * 8 + it;
    const float* xr = x + (size_t)n * DIM;
    float part[NE];
#pragma unroll
    for (int e = 0; e < NE; ++e) part[e] = 0.f;
#pragma unroll
    for (int c = 0; c < DIM / 64; ++c) {
      float xv = xr[c * 64 + lane];
#pragma unroll
      for (int e = 0; e < NE; ++e) part[e] += xv * Wl[e * DIM + c * 64 + lane];
    }
#pragma unroll
    for (int off = 32; off > 0; off >>= 1) {
#pragma unroll
      for (int e = 0; e < NE; ++e) part[e] += __shfl_xor(part[e], off);
    }
    // top-2, ties -> lower index (lax.top_k semantics)
    int e0 = 0; float v0 = part[0];
#pragma unroll
    for (int e = 1; e < NE; ++e) if (part[e] > v0) { v0 = part[e]; e0 = e; }
    int e1 = -1; float v1 = -3.4e38f;
#pragma unroll
    for (int e = 0; e < NE; ++e) if (e != e0 && part[e] > v1) { v1 = part[e]; e1 = e; }

    float pexp[NE]; float s = 0.f;
#pragma unroll
    for (int e = 0; e < NE; ++e) { pexp[e] = expf(part[e] - v0); s += pexp[e]; }
    const float inv = 1.0f / s;
    const float pr = inv;               // exp(0)*inv -> top-1 prob = priority
    float w1v = 0.f;
#pragma unroll
    for (int e = 0; e < NE; ++e) if (e == e1) w1v = pexp[e] * inv;

    // per-lane-expert double accumulation: lane e accumulates expert e
    float myl = 0.f, mypexp = 0.f;
#pragma unroll
    for (int e = 0; e < NE; ++e) if (lane == e) { myl = part[e]; mypexp = pexp[e]; }
    if (lane < NE) {
      my_imp  += (double)(mypexp * inv);
      // 1 - Phi((thr - logit)/NOISE_STD) = 0.5*erfc((thr-logit)/(0.125*sqrt(2)))
      my_load += (double)(0.5f * erfcf((v1 - myl) * 5.656854249492380f));
    }
    if (lane == 0) {
      int p0 = atomicAdd(&list_len[e0], 1);
      int p1 = atomicAdd(&list_len[e1], 1);
      aidx[e0 * AMAX + p0]   = n * 2;
      keyarr[e0 * AMAX + p0] = (float)(e0 * 4) - pr;            // e*(K+2) - score, fp32 like ref
      warr[e0 * AMAX + p0]   = pr;
      aidx[e1 * AMAX + p1]   = n * 2 + 1;
      keyarr[e1 * AMAX + p1] = (float)(e1 * 4) - (pr - 1.0f);
      warr[e1 * AMAX + p1]   = w1v;
    }
  }
  if (lane < NE) {
    unsafeAtomicAdd(&imp[lane], my_imp);
    unsafeAtomicAdd(&loadacc[lane], my_load);
  }
}

// ---------------- capacity keep/compact + scalar outputs -------------------------------
__global__ __launch_bounds__(256) void compact_kernel(
    const int* __restrict__ list_len, const int* __restrict__ aidx,
    const float* __restrict__ keyarr, const float* __restrict__ warr,
    int* __restrict__ dtok, float* __restrict__ dw,
    const double* __restrict__ imp, const double* __restrict__ loadacc,
    float* __restrict__ out_scalars)
{
  __shared__ float sk[6144];
  __shared__ int   sa[6144];
  const int e = blockIdx.x, tid = threadIdx.x;
  const int C = list_len[e];
  if (C <= CAP) {
    // nothing dropped for this expert: keep-set = all, slot order is free
    for (int t = tid; t < C; t += 256) {
      int a = aidx[e * AMAX + t];
      dtok[e * CAP + t] = a >> 1;
      dw[e * CAP + t]   = warr[e * AMAX + t];
    }
  } else {
    const bool useL = (C <= 6144);
    if (useL) {
      for (int t = tid; t < C; t += 256) { sk[t] = keyarr[e*AMAX+t]; sa[t] = aidx[e*AMAX+t]; }
      __syncthreads();
    }
    for (int t = tid; t < C; t += 256) {
      float kt = keyarr[e*AMAX+t]; int at = aidx[e*AMAX+t];
      int r = 0;
      for (int u = 0; u < C; ++u) {
        float ku = useL ? sk[u] : keyarr[e*AMAX+u];
        int   au = useL ? sa[u] : aidx[e*AMAX+u];
        if (ku < kt || (ku == kt && au < at)) ++r;   // stable by assignment index
      }
      if (r < CAP) { dtok[e*CAP + r] = at >> 1; dw[e*CAP + r] = warr[e*AMAX+t]; }
    }
  }
  if (e == 0 && tid == 0) {
    double mi = 0, ml = 0;
    for (int i = 0; i < NE; ++i) { mi += imp[i]; ml += loadacc[i]; }
    mi /= NE; ml /= NE;
    double vi = 0, vl = 0;
    for (int i = 0; i < NE; ++i) {
      double di = imp[i] - mi;     vi += di * di;
      double dl = loadacc[i] - ml; vl += dl * dl;
    }
    vi /= NE; vl /= NE;
    double li = vi / (mi * mi + 1e-6), ll = vl / (ml * ml + 1e-6);
    out_scalars[0] = (float)(0.5 * (li + ll));     // aux_loss
    int drop = 0;
    for (int i = 0; i < NE; ++i) { int c2 = list_len[i]; if (c2 > CAP) drop += c2 - CAP; }
    out_scalars[1] = (float)drop;                  // dropped
    for (int i = 0; i < NE; ++i) out_scalars[2 + i] = (float)list_len[i];  // expert_counts
  }
}

// ---------------- gather kept rows into padded bf16 A buffer [E][CAP][DIM] -------------
__global__ __launch_bounds__(256) void gather_kernel(
    const float* __restrict__ x, const int* __restrict__ dtok,
    const int* __restrict__ list_len, __bf16* __restrict__ Ag)
{
  const int row  = blockIdx.x * 4 + (threadIdx.x >> 6);
  const int lane = threadIdx.x & 63;
  const int e = row / CAP, slot = row - e * CAP;
  const int kept = min(list_len[e], CAP);
  __bf16* dst = Ag + (size_t)row * DIM;
  if (slot < kept) {
    const float* srcr = x + (size_t)dtok[e * CAP + slot] * DIM;
#pragma unroll
    for (int c = 0; c < DIM / 128; ++c) {
      float2 v = *(const float2*)(srcr + c * 128 + lane * 2);
      bf16x2 o; o[0] = (__bf16)v.x; o[1] = (__bf16)v.y;
      *(bf16x2*)(dst + c * 128 + lane * 2) = o;
    }
  } else {
    bf16x2 z; z[0] = (__bf16)0.f; z[1] = (__bf16)0.f;
#pragma unroll
    for (int c = 0; c < DIM / 128; ++c) *(bf16x2*)(dst + c * 128 + lane * 2) = z;
  }
}

// ---------------- grouped GEMM: C[M,N] = A[M,K] * BT[N,K]^T, BK=64, XCD-swizzled -------
// MODE 0: h = gelu_exact(A*B + bias), store bf16.   MODE 1: atomic scatter w*(A*B+bias).
// Block mapping: i = blockIdx.x; xcd = i&7; q = i>>3; tm = q % tilesM; pgrp = q / tilesM;
// pair p = pgrp*8 + xcd; e = p / tilesN; tn = p % tilesN.
// => all tm of a given (e,tn) land on one XCD (blockIdx%8 round-robin heuristic),
//    so the B-tile stays L2-resident; consecutive pairs on an XCD share the same e,
//    so the expert's A panel stays L2-warm too.
template<int MODE>
__global__ __launch_bounds__(256) void moe_gemm(
    const __bf16* __restrict__ Aall, const __bf16* __restrict__ BTall,
    const float* __restrict__ bias, __bf16* __restrict__ Hout,
    float* __restrict__ Out, const int* __restrict__ dtok, const float* __restrict__ dww,
    const int* __restrict__ list_len, int Kd, int Nd, int tilesM, int tilesN)
{
  const int i_blk = blockIdx.x;
  const int xcd = i_blk & 7, q = i_blk >> 3;
  const int tm = q % tilesM, pgrp = q / tilesM;
  const int p = pgrp * 8 + xcd;
  const int e = p / tilesN, tn = p % tilesN;

  const int kept = min(list_len[e], CAP);
  const int mUsed = (kept + 127) >> 7;
  if (tm >= mUsed) return;

  // BK=64: two k-chunks of 32. Chunk c at offset c*4096 elements.
  __shared__ __bf16 As[2 * 8 * 512];   // 16 KB
  __shared__ __bf16 Bs[2 * 8 * 512];   // 16 KB

  const int tid = threadIdx.x, lane = tid & 63, wave = tid >> 6;
  const int wm = wave & 1, wn = wave >> 1;
  const int m0 = tm * 128, n0 = tn * 128;

  const __bf16* Ae = Aall + (size_t)e * CAP * Kd;
  const __bf16* Be = BTall + (size_t)e * Nd * Kd;

  const int lr = lane & 15, lc = (lane >> 4) * 8;
  const __bf16* pA[4]; const __bf16* pB[4];
  __bf16* lA[4]; __bf16* lB[4];
#pragma unroll
  for (int c = 0; c < 2; ++c) {
#pragma unroll
    for (int g = 0; g < 2; ++g) {
      const int t = c * 2 + g;
      pA[t] = Ae + (size_t)(m0 + (wave * 2 + g) * 16 + lr) * Kd + c * 32 + lc;
      pB[t] = Be + (size_t)(n0 + (wave * 2 + g) * 16 + lr) * Kd + c * 32 + lc;
      lA[t] = &As[c * 4096 + (wave * 2 + g) * 512];
      lB[t] = &Bs[c * 4096 + (wave * 2 + g) * 512];
    }
  }

  floatx4 acc[4][4];
#pragma unroll
  for (int i = 0; i < 4; ++i)
#pragma unroll
    for (int j = 0; j < 4; ++j) acc[i][j] = (floatx4)0.f;

  const int kIters = Kd >> 6;
  for (int kt = 0; kt < kIters; ++kt) {
#pragma unroll
    for (int t = 0; t < 4; ++t) {
      gl_lds16(pA[t], lA[t]); gl_lds16(pB[t], lB[t]);
      pA[t] += 64; pB[t] += 64;
    }
    __syncthreads();                       // drains vmcnt before ds_read
#pragma unroll
    for (int c = 0; c < 2; ++c) {
      bf16x8 af[4], bfr[4];
#pragma unroll
      for (int i = 0; i < 4; ++i) af[i]  = *(const bf16x8*)(&As[c * 4096 + ((wm * 4 + i) * 64 + lane) * 8]);
#pragma unroll
      for (int j = 0; j < 4; ++j) bfr[j] = *(const bf16x8*)(&Bs[c * 4096 + ((wn * 4 + j) * 64 + lane) * 8]);
#pragma unroll
      for (int i = 0; i < 4; ++i)
#pragma unroll
        for (int j = 0; j < 4; ++j)
          acc[i][j] = __builtin_amdgcn_mfma_f32_16x16x32_bf16(af[i], bfr[j], acc[i][j], 0, 0, 0);
    }
    __syncthreads();
  }

  const int quad = lane >> 4, lcol = lane & 15;
  float bcol[4];
#pragma unroll
  for (int j = 0; j < 4; ++j) bcol[j] = bias[e * Nd + n0 + wn * 64 + j * 16 + lcol];

  if (MODE == 0) {
#pragma unroll
    for (int i = 0; i < 4; ++i) {
#pragma unroll
      for (int r = 0; r < 4; ++r) {
        const int row = m0 + wm * 64 + i * 16 + quad * 4 + r;  // C/D: row=(l>>4)*4+reg, col=l&15
        __bf16* hrow = Hout + ((size_t)(e * CAP + row)) * Nd;
#pragma unroll
        for (int j = 0; j < 4; ++j) {
          float v = acc[i][j][r] + bcol[j];
          float g = 0.5f * v * (1.0f + erff(v * 0.7071067811865475f));
          hrow[n0 + wn * 64 + j * 16 + lcol] = (__bf16)g;
        }
      }
    }
  } else {
#pragma unroll
    for (int i = 0; i < 4; ++i) {
#pragma unroll
      for (int r = 0; r < 4; ++r) {
        const int row = m0 + wm * 64 + i * 16 + quad * 4 + r;
        const float w = dww[e * CAP + row];
        if (w != 0.0f) {
          const int tok = dtok[e * CAP + row];
          float* orow = Out + (size_t)tok * DIM;
#pragma unroll
          for (int j = 0; j < 4; ++j) {
            float v = w * (acc[i][j][r] + bcol[j]);
            unsafeAtomicAdd(&orow[n0 + wn * 64 + j * 16 + lcol], v);
          }
        }
      }
    }
  }
}

extern "C" void kernel_launch(void* const* d_in, const int* in_sizes, int n_in,
                              void* d_out, int out_size, void* d_ws, size_t ws_size,
                              hipStream_t stream) {
  (void)in_sizes; (void)n_in; (void)out_size; (void)ws_size;
  const float* x  = (const float*)d_in[0];
  const float* rw = (const float*)d_in[1];
  const float* w1 = (const float*)d_in[2];
  const float* b1 = (const float*)d_in[3];
  const float* w2 = (const float*)d_in[4];
  const float* b2 = (const float*)d_in[5];
  float* out = (float*)d_out;
  char* ws = (char*)d_ws;

  // ws layout (224 MiB total)
  int*    list_len = (int*)(ws + 0);
  double* imp      = (double*)(ws + 64);
  double* loadacc  = (double*)(ws + 128);
  int*    dtok     = (int*)(ws + 256);
  float*  dw       = (float*)(ws + 256 + 81920);
  int*    aidx     = (int*)(ws + 164096);
  float*  keyarr   = (float*)(ws + 164096 + 524288);
  float*  warr     = (float*)(ws + 164096 + 1048576);
  __bf16* W1T      = (__bf16*)(ws + 2097152);
  __bf16* W2T      = (__bf16*)(ws + 2097152 + 37748736);
  __bf16* Ag       = (__bf16*)(ws + 2097152 + 2 * 37748736);
  __bf16* hbuf     = (__bf16*)(ws + 2097152 + 2 * 37748736 + 31457280);

  hipMemsetAsync(d_out, 0, (size_t)NTOK * DIM * sizeof(float), stream);  // atomic-add target
  hipMemsetAsync(ws, 0, 164096, stream);                                 // counters + dispatch bufs

  transpose_conv<<<dim3(576, 8), 256, 0, stream>>>(w1, W1T, DIM, HDIM);
  transpose_conv<<<dim3(576, 8), 256, 0, stream>>>(w2, W2T, HDIM, DIM);
  router_kernel<<<NTOK / 32, 256, 0, stream>>>(x, rw, list_len, imp, loadacc, aidx, keyarr, warr);
  compact_kernel<<<NE, 256, 0, stream>>>(list_len, aidx, keyarr, warr, dtok, dw, imp, loadacc,
                                         out + (size_t)NTOK * DIM);
  gather_kernel<<<(NE * CAP) / 4, 256, 0, stream>>>(x, dtok, list_len, Ag);
  // FC1: tilesM=20, tilesN=HDIM/128=24 -> 3840 blocks (flat, XCD-swizzled)
  moe_gemm<0><<<NE * 20 * (HDIM / 128), 256, 0, stream>>>(
      Ag, W1T, b1, hbuf, nullptr, nullptr, nullptr, list_len, DIM, HDIM, 20, HDIM / 128);
  // FC2: tilesM=20, tilesN=DIM/128=6 -> 960 blocks
  moe_gemm<1><<<NE * 20 * (DIM / 128), 256, 0, stream>>>(
      hbuf, W2T, b2, nullptr, out, dtok, dw, list_len, HDIM, DIM, 20, DIM / 128);
}

// Round 3
// 799.941 us; speedup vs baseline: 1.0979x; 1.0449x over previous
//
#include <hip/hip_runtime.h>
#include <hip/hip_bf16.h>
#include <math.h>

#define NTOK 8192
#define DIM  768
#define HDIM 3072
#define NE   8
#define CAP  2560
#define AMAX 16384

typedef __bf16 bf16x8  __attribute__((ext_vector_type(8)));
typedef __bf16 bf16x2  __attribute__((ext_vector_type(2)));
typedef float  floatx4 __attribute__((ext_vector_type(4)));

typedef unsigned int u32_g __attribute__((address_space(1)));
typedef unsigned int u32_l __attribute__((address_space(3)));

__device__ __forceinline__ void gl_lds16(const void* g, void* l) {
  // 16B per lane, LDS dest = wave-uniform base + lane*16
  __builtin_amdgcn_global_load_lds((const u32_g*)g, (u32_l*)l, 16, 0, 0);
}

// gelu exact via A&S 7.1.26 erf poly (|err| < 1.5e-7), ~12 VALU vs libm erff
__device__ __forceinline__ float gelu_exact(float v) {
  float z = fabsf(v) * 0.7071067811865475f;
  float t = __builtin_amdgcn_rcpf(1.0f + 0.3275911f * z);
  float p = ((((1.061405429f * t - 1.453152027f) * t + 1.421413741f) * t
              - 0.284496736f) * t + 0.254829592f) * t;
  float e = 1.0f - p * __expf(-z * z);
  e = copysignf(e, v);
  return 0.5f * v * (1.0f + e);
}

// ---------------- fused weight transpose + fp32->bf16: [E][K][N] -> [E][N][K] ----------
__global__ __launch_bounds__(256) void transpose_conv2(
    const float* __restrict__ w1, const float* __restrict__ w2,
    __bf16* __restrict__ o1, __bf16* __restrict__ o2)
{
  const int which = blockIdx.z;
  const float* src = which ? w2 : w1;
  __bf16* dst = which ? o2 : o1;
  const int Kd = which ? HDIM : DIM;
  const int Nd = which ? DIM : HDIM;
  const int e = blockIdx.y;
  const int tilesK = Kd >> 6;
  const int bk = blockIdx.x % tilesK, bn = blockIdx.x / tilesK;
  __shared__ float T[64][65];
  const float* se = src + (size_t)e * Kd * Nd;
  const int k0 = bk * 64, n0 = bn * 64;
  const int tid = threadIdx.x;
#pragma unroll
  for (int it = 0; it < 16; ++it) {
    int flat = tid + it * 256;
    int kk = flat >> 6, nn = flat & 63;
    T[kk][nn] = se[(size_t)(k0 + kk) * Nd + n0 + nn];
  }
  __syncthreads();
  const int n = tid >> 2, kg = tid & 3;
  bf16x8 v0, v1;
#pragma unroll
  for (int q = 0; q < 8; ++q) v0[q] = (__bf16)T[kg * 16 + q][n];
#pragma unroll
  for (int q = 0; q < 8; ++q) v1[q] = (__bf16)T[kg * 16 + 8 + q][n];
  __bf16* de = dst + (size_t)e * Nd * Kd + (size_t)(n0 + n) * Kd + k0 + kg * 16;
  *(bf16x8*)(de) = v0;
  *(bf16x8*)(de + 8) = v1;
}

// ---------------- router: logits, softmax, top-2, aux stats, assignment lists ----------
__global__ __launch_bounds__(256) void router_kernel(
    const float* __restrict__ x, const float* __restrict__ rw,
    int* __restrict__ list_len, double* __restrict__ imp, double* __restrict__ loadacc,
    int* __restrict__ aidx, float* __restrict__ keyarr, float* __restrict__ warr)
{
  __shared__ float Wl[NE * DIM];   // Wl[e*DIM+d] = rw[d*NE+e]
  const int tid = threadIdx.x;
  for (int i = tid; i < NE * DIM; i += 256) {
    int e = i / DIM, d = i - e * DIM;
    Wl[i] = rw[d * NE + e];
  }
  __syncthreads();
  const int wave = tid >> 6, lane = tid & 63;
  double my_imp = 0.0, my_load = 0.0;

  for (int it = 0; it < 8; ++it) {
    const int n = blockIdx.x * 32 + wave * 8 + it;
    const float* xr = x + (size_t)n * DIM;
    float part[NE];
#pragma unroll
    for (int e = 0; e < NE; ++e) part[e] = 0.f;
#pragma unroll
    for (int c = 0; c < DIM / 64; ++c) {
      float xv = xr[c * 64 + lane];
#pragma unroll
      for (int e = 0; e < NE; ++e) part[e] += xv * Wl[e * DIM + c * 64 + lane];
    }
#pragma unroll
    for (int off = 32; off > 0; off >>= 1) {
#pragma unroll
      for (int e = 0; e < NE; ++e) part[e] += __shfl_xor(part[e], off);
    }
    // top-2, ties -> lower index (lax.top_k semantics)
    int e0 = 0; float v0 = part[0];
#pragma unroll
    for (int e = 1; e < NE; ++e) if (part[e] > v0) { v0 = part[e]; e0 = e; }
    int e1 = -1; float v1 = -3.4e38f;
#pragma unroll
    for (int e = 0; e < NE; ++e) if (e != e0 && part[e] > v1) { v1 = part[e]; e1 = e; }

    float pexp[NE]; float s = 0.f;
#pragma unroll
    for (int e = 0; e < NE; ++e) { pexp[e] = expf(part[e] - v0); s += pexp[e]; }
    const float inv = 1.0f / s;
    const float pr = inv;               // exp(0)*inv -> top-1 prob = priority
    float w1v = 0.f;
#pragma unroll
    for (int e = 0; e < NE; ++e) if (e == e1) w1v = pexp[e] * inv;

    // per-lane-expert double accumulation: lane e accumulates expert e
    float myl = 0.f, mypexp = 0.f;
#pragma unroll
    for (int e = 0; e < NE; ++e) if (lane == e) { myl = part[e]; mypexp = pexp[e]; }
    if (lane < NE) {
      my_imp  += (double)(mypexp * inv);
      // 1 - Phi((thr - logit)/NOISE_STD) = 0.5*erfc((thr-logit)/(0.125*sqrt(2)))
      my_load += (double)(0.5f * erfcf((v1 - myl) * 5.656854249492380f));
    }
    if (lane == 0) {
      int p0 = atomicAdd(&list_len[e0], 1);
      int p1 = atomicAdd(&list_len[e1], 1);
      aidx[e0 * AMAX + p0]   = n * 2;
      keyarr[e0 * AMAX + p0] = (float)(e0 * 4) - pr;            // e*(K+2) - score, fp32 like ref
      warr[e0 * AMAX + p0]   = pr;
      aidx[e1 * AMAX + p1]   = n * 2 + 1;
      keyarr[e1 * AMAX + p1] = (float)(e1 * 4) - (pr - 1.0f);
      warr[e1 * AMAX + p1]   = w1v;
    }
  }
  if (lane < NE) {
    unsafeAtomicAdd(&imp[lane], my_imp);
    unsafeAtomicAdd(&loadacc[lane], my_load);
  }
}

// ---------------- capacity keep/compact + scalar outputs -------------------------------
__global__ __launch_bounds__(256) void compact_kernel(
    const int* __restrict__ list_len, const int* __restrict__ aidx,
    const float* __restrict__ keyarr, const float* __restrict__ warr,
    int* __restrict__ dtok, float* __restrict__ dw,
    const double* __restrict__ imp, const double* __restrict__ loadacc,
    float* __restrict__ out_scalars)
{
  __shared__ float sk[6144];
  __shared__ int   sa[6144];
  const int e = blockIdx.x, tid = threadIdx.x;
  const int C = list_len[e];
  if (C <= CAP) {
    // nothing dropped for this expert: keep-set = all, slot order is free
    for (int t = tid; t < C; t += 256) {
      int a = aidx[e * AMAX + t];
      dtok[e * CAP + t] = a >> 1;
      dw[e * CAP + t]   = warr[e * AMAX + t];
    }
  } else {
    const bool useL = (C <= 6144);
    if (useL) {
      for (int t = tid; t < C; t += 256) { sk[t] = keyarr[e*AMAX+t]; sa[t] = aidx[e*AMAX+t]; }
      __syncthreads();
    }
    for (int t = tid; t < C; t += 256) {
      float kt = keyarr[e*AMAX+t]; int at = aidx[e*AMAX+t];
      int r = 0;
      for (int u = 0; u < C; ++u) {
        float ku = useL ? sk[u] : keyarr[e*AMAX+u];
        int   au = useL ? sa[u] : aidx[e*AMAX+u];
        if (ku < kt || (ku == kt && au < at)) ++r;   // stable by assignment index
      }
      if (r < CAP) { dtok[e*CAP + r] = at >> 1; dw[e*CAP + r] = warr[e*AMAX+t]; }
    }
  }
  if (e == 0 && tid == 0) {
    double mi = 0, ml = 0;
    for (int i = 0; i < NE; ++i) { mi += imp[i]; ml += loadacc[i]; }
    mi /= NE; ml /= NE;
    double vi = 0, vl = 0;
    for (int i = 0; i < NE; ++i) {
      double di = imp[i] - mi;     vi += di * di;
      double dl = loadacc[i] - ml; vl += dl * dl;
    }
    vi /= NE; vl /= NE;
    double li = vi / (mi * mi + 1e-6), ll = vl / (ml * ml + 1e-6);
    out_scalars[0] = (float)(0.5 * (li + ll));     // aux_loss
    int drop = 0;
    for (int i = 0; i < NE; ++i) { int c2 = list_len[i]; if (c2 > CAP) drop += c2 - CAP; }
    out_scalars[1] = (float)drop;                  // dropped
    for (int i = 0; i < NE; ++i) out_scalars[2 + i] = (float)list_len[i];  // expert_counts
  }
}

// ---------------- gather kept rows into padded bf16 A buffer [E][CAP][DIM] -------------
__global__ __launch_bounds__(256) void gather_kernel(
    const float* __restrict__ x, const int* __restrict__ dtok,
    const int* __restrict__ list_len, __bf16* __restrict__ Ag)
{
  const int row  = blockIdx.x * 4 + (threadIdx.x >> 6);
  const int lane = threadIdx.x & 63;
  const int e = row / CAP, slot = row - e * CAP;
  const int kept = min(list_len[e], CAP);
  __bf16* dst = Ag + (size_t)row * DIM;
  if (slot < kept) {
    const float* srcr = x + (size_t)dtok[e * CAP + slot] * DIM;
#pragma unroll
    for (int c = 0; c < DIM / 128; ++c) {
      float2 v = *(const float2*)(srcr + c * 128 + lane * 2);
      bf16x2 o; o[0] = (__bf16)v.x; o[1] = (__bf16)v.y;
      *(bf16x2*)(dst + c * 128 + lane * 2) = o;
    }
  } else {
    bf16x2 z; z[0] = (__bf16)0.f; z[1] = (__bf16)0.f;
#pragma unroll
    for (int c = 0; c < DIM / 128; ++c) *(bf16x2*)(dst + c * 128 + lane * 2) = z;
  }
}

// ---------------- grouped GEMM: C[M,N] = A[M,K] * BT[N,K]^T --------------------------
// Depth-2 global_load_lds pipeline: 3 LDS buffers (BK=32), raw s_barrier + manual
// s_waitcnt vmcnt(4) so prefetch loads stay in flight across the barrier
// (AITER-style; m139-validated raw-barrier pattern).
// MODE 0 (FC1, tilesN==24): e=xcd, tn=pgrp -> expert A panel (3.9MB) L2-resident.
// MODE 1 (FC2): interleaved pair mapping (round-2 scheme).
template<int MODE>
__global__ __launch_bounds__(256, 3) void moe_gemm(
    const __bf16* __restrict__ Aall, const __bf16* __restrict__ BTall,
    const float* __restrict__ bias, __bf16* __restrict__ Hout,
    float* __restrict__ Out, const int* __restrict__ dtok, const float* __restrict__ dww,
    const int* __restrict__ list_len, int Kd, int Nd, int tilesM, int tilesN)
{
  const int i_blk = blockIdx.x;
  const int xcd = i_blk & 7, q = i_blk >> 3;
  const int tm = q % tilesM, pgrp = q / tilesM;
  int e, tn;
  if (MODE == 0) {            // FC1: one expert per XCD (pairs_per_xcd == tilesN == 24)
    e = xcd; tn = pgrp;
  } else {
    const int p = pgrp * 8 + xcd;
    e = p / tilesN; tn = p % tilesN;
  }

  const int kept = min(list_len[e], CAP);
  const int mUsed = (kept + 127) >> 7;
  if (tm >= mUsed) return;

  // 3 buffers x (A 4096 + B 4096 bf16) = 48 KB
  __shared__ __bf16 S[3][8192];

  const int tid = threadIdx.x, lane = tid & 63, wave = tid >> 6;
  const int wm = wave & 1, wn = wave >> 1;
  const int m0 = tm * 128, n0 = tn * 128;

  const __bf16* Ae = Aall + (size_t)e * CAP * Kd;
  const __bf16* Be = BTall + (size_t)e * Nd * Kd;

  const int lr = lane & 15, lc = (lane >> 4) * 8;
  const __bf16* gA0 = Ae + (size_t)(m0 + (wave * 2 + 0) * 16 + lr) * Kd + lc;
  const __bf16* gA1 = Ae + (size_t)(m0 + (wave * 2 + 1) * 16 + lr) * Kd + lc;
  const __bf16* gB0 = Be + (size_t)(n0 + (wave * 2 + 0) * 16 + lr) * Kd + lc;
  const __bf16* gB1 = Be + (size_t)(n0 + (wave * 2 + 1) * 16 + lr) * Kd + lc;
  const int sA0 = (wave * 2 + 0) * 512, sA1 = (wave * 2 + 1) * 512;
  const int sB0 = 4096 + sA0, sB1 = 4096 + sA1;

  floatx4 acc[4][4];
#pragma unroll
  for (int i = 0; i < 4; ++i)
#pragma unroll
    for (int j = 0; j < 4; ++j) acc[i][j] = (floatx4)0.f;

  const int kIters = Kd >> 5;

#define ISSUE(J, B)                                            \
  do {                                                         \
    const int _off = (J) * 32;                                 \
    gl_lds16(gA0 + _off, &S[(B)][sA0]);                        \
    gl_lds16(gA1 + _off, &S[(B)][sA1]);                        \
    gl_lds16(gB0 + _off, &S[(B)][sB0]);                        \
    gl_lds16(gB1 + _off, &S[(B)][sB1]);                        \
  } while (0)

  ISSUE(0, 0);
  ISSUE(1, 1);
  int cur = 0;
  for (int kt = 0; kt < kIters; ++kt) {
    // wait for buffer `cur` loads (issued 2 iters ago): <=4 outstanding = next batch only
    if (kt < kIters - 1) __builtin_amdgcn_s_waitcnt(0x0F74);   // vmcnt(4)
    else                 __builtin_amdgcn_s_waitcnt(0x0F70);   // vmcnt(0)
    asm volatile("" ::: "memory");
    __builtin_amdgcn_s_barrier();
    asm volatile("" ::: "memory");

    bf16x8 af[4], bfr[4];
#pragma unroll
    for (int i = 0; i < 4; ++i) af[i]  = *(const bf16x8*)(&S[cur][((wm * 4 + i) * 64 + lane) * 8]);
#pragma unroll
    for (int j = 0; j < 4; ++j) bfr[j] = *(const bf16x8*)(&S[cur][4096 + ((wn * 4 + j) * 64 + lane) * 8]);

    if (kt + 2 < kIters) {
      int nb = cur + 2; if (nb >= 3) nb -= 3;
      ISSUE(kt + 2, nb);
    }

#pragma unroll
    for (int i = 0; i < 4; ++i)
#pragma unroll
      for (int j = 0; j < 4; ++j)
        acc[i][j] = __builtin_amdgcn_mfma_f32_16x16x32_bf16(af[i], bfr[j], acc[i][j], 0, 0, 0);

    cur = (cur == 2) ? 0 : cur + 1;
  }
#undef ISSUE

  const int quad = lane >> 4, lcol = lane & 15;
  float bcol[4];
#pragma unroll
  for (int j = 0; j < 4; ++j) bcol[j] = bias[e * Nd + n0 + wn * 64 + j * 16 + lcol];

  if (MODE == 0) {
#pragma unroll
    for (int i = 0; i < 4; ++i) {
#pragma unroll
      for (int r = 0; r < 4; ++r) {
        const int row = m0 + wm * 64 + i * 16 + quad * 4 + r;  // C/D: row=(l>>4)*4+reg, col=l&15
        __bf16* hrow = Hout + ((size_t)(e * CAP + row)) * Nd;
#pragma unroll
        for (int j = 0; j < 4; ++j) {
          float v = acc[i][j][r] + bcol[j];
          hrow[n0 + wn * 64 + j * 16 + lcol] = (__bf16)gelu_exact(v);
        }
      }
    }
  } else {
#pragma unroll
    for (int i = 0; i < 4; ++i) {
#pragma unroll
      for (int r = 0; r < 4; ++r) {
        const int row = m0 + wm * 64 + i * 16 + quad * 4 + r;
        const float w = dww[e * CAP + row];
        if (w != 0.0f) {
          const int tok = dtok[e * CAP + row];
          float* orow = Out + (size_t)tok * DIM;
#pragma unroll
          for (int j = 0; j < 4; ++j) {
            float v = w * (acc[i][j][r] + bcol[j]);
            unsafeAtomicAdd(&orow[n0 + wn * 64 + j * 16 + lcol], v);
          }
        }
      }
    }
  }
}

extern "C" void kernel_launch(void* const* d_in, const int* in_sizes, int n_in,
                              void* d_out, int out_size, void* d_ws, size_t ws_size,
                              hipStream_t stream) {
  (void)in_sizes; (void)n_in; (void)out_size; (void)ws_size;
  const float* x  = (const float*)d_in[0];
  const float* rw = (const float*)d_in[1];
  const float* w1 = (const float*)d_in[2];
  const float* b1 = (const float*)d_in[3];
  const float* w2 = (const float*)d_in[4];
  const float* b2 = (const float*)d_in[5];
  float* out = (float*)d_out;
  char* ws = (char*)d_ws;

  // ws layout (224 MiB total)
  int*    list_len = (int*)(ws + 0);
  double* imp      = (double*)(ws + 64);
  double* loadacc  = (double*)(ws + 128);
  int*    dtok     = (int*)(ws + 256);
  float*  dw       = (float*)(ws + 256 + 81920);
  int*    aidx     = (int*)(ws + 164096);
  float*  keyarr   = (float*)(ws + 164096 + 524288);
  float*  warr     = (float*)(ws + 164096 + 1048576);
  __bf16* W1T      = (__bf16*)(ws + 2097152);
  __bf16* W2T      = (__bf16*)(ws + 2097152 + 37748736);
  __bf16* Ag       = (__bf16*)(ws + 2097152 + 2 * 37748736);
  __bf16* hbuf     = (__bf16*)(ws + 2097152 + 2 * 37748736 + 31457280);

  hipMemsetAsync(d_out, 0, (size_t)NTOK * DIM * sizeof(float), stream);  // atomic-add target
  hipMemsetAsync(ws, 0, 164096, stream);                                 // counters + dispatch bufs

  transpose_conv2<<<dim3(576, 8, 2), 256, 0, stream>>>(w1, w2, W1T, W2T);
  router_kernel<<<NTOK / 32, 256, 0, stream>>>(x, rw, list_len, imp, loadacc, aidx, keyarr, warr);
  compact_kernel<<<NE, 256, 0, stream>>>(list_len, aidx, keyarr, warr, dtok, dw, imp, loadacc,
                                         out + (size_t)NTOK * DIM);
  gather_kernel<<<(NE * CAP) / 4, 256, 0, stream>>>(x, dtok, list_len, Ag);
  // FC1: tilesM=20, tilesN=HDIM/128=24 -> 3840 blocks; e=xcd mapping
  moe_gemm<0><<<NE * 20 * (HDIM / 128), 256, 0, stream>>>(
      Ag, W1T, b1, hbuf, nullptr, nullptr, nullptr, list_len, DIM, HDIM, 20, HDIM / 128);
  // FC2: tilesM=20, tilesN=DIM/128=6 -> 960 blocks; interleaved mapping
  moe_gemm<1><<<NE * 20 * (DIM / 128), 256, 0, stream>>>(
      hbuf, W2T, b2, nullptr, out, dtok, dw, list_len, HDIM, DIM, 20, DIM / 128);
}

// Round 4
// 746.898 us; speedup vs baseline: 1.1759x; 1.0710x over previous
//
#include <hip/hip_runtime.h>
#include <hip/hip_bf16.h>
#include <math.h>

#define NTOK 8192
#define DIM  768
#define HDIM 3072
#define NE   8
#define CAP  2560
#define AMAX 16384

typedef __bf16 bf16x8  __attribute__((ext_vector_type(8)));
typedef __bf16 bf16x2  __attribute__((ext_vector_type(2)));
typedef float  floatx4 __attribute__((ext_vector_type(4)));

typedef unsigned int u32_g __attribute__((address_space(1)));
typedef unsigned int u32_l __attribute__((address_space(3)));

__device__ __forceinline__ void gl_lds16(const void* g, void* l) {
  // 16B per lane, LDS dest = wave-uniform base + lane*16
  __builtin_amdgcn_global_load_lds((const u32_g*)g, (u32_l*)l, 16, 0, 0);
}

// gelu exact via A&S 7.1.26 erf poly (|err| < 1.5e-7)
__device__ __forceinline__ float gelu_exact(float v) {
  float z = fabsf(v) * 0.7071067811865475f;
  float t = __builtin_amdgcn_rcpf(1.0f + 0.3275911f * z);
  float p = ((((1.061405429f * t - 1.453152027f) * t + 1.421413741f) * t
              - 0.284496736f) * t + 0.254829592f) * t;
  float e = 1.0f - p * __expf(-z * z);
  e = copysignf(e, v);
  return 0.5f * v * (1.0f + e);
}

// ---------------- fused weight transpose + fp32->bf16: [E][K][N] -> [E][N][K] ----------
__global__ __launch_bounds__(256) void transpose_conv2(
    const float* __restrict__ w1, const float* __restrict__ w2,
    __bf16* __restrict__ o1, __bf16* __restrict__ o2)
{
  const int which = blockIdx.z;
  const float* src = which ? w2 : w1;
  __bf16* dst = which ? o2 : o1;
  const int Kd = which ? HDIM : DIM;
  const int Nd = which ? DIM : HDIM;
  const int e = blockIdx.y;
  const int tilesK = Kd >> 6;
  const int bk = blockIdx.x % tilesK, bn = blockIdx.x / tilesK;
  __shared__ float T[64][65];
  const float* se = src + (size_t)e * Kd * Nd;
  const int k0 = bk * 64, n0 = bn * 64;
  const int tid = threadIdx.x;
#pragma unroll
  for (int it = 0; it < 16; ++it) {
    int flat = tid + it * 256;
    int kk = flat >> 6, nn = flat & 63;
    T[kk][nn] = se[(size_t)(k0 + kk) * Nd + n0 + nn];
  }
  __syncthreads();
  const int n = tid >> 2, kg = tid & 3;
  bf16x8 v0, v1;
#pragma unroll
  for (int q = 0; q < 8; ++q) v0[q] = (__bf16)T[kg * 16 + q][n];
#pragma unroll
  for (int q = 0; q < 8; ++q) v1[q] = (__bf16)T[kg * 16 + 8 + q][n];
  __bf16* de = dst + (size_t)e * Nd * Kd + (size_t)(n0 + n) * Kd + k0 + kg * 16;
  *(bf16x8*)(de) = v0;
  *(bf16x8*)(de + 8) = v1;
}

// ---------------- router ---------------------------------------------------------------
__global__ __launch_bounds__(256) void router_kernel(
    const float* __restrict__ x, const float* __restrict__ rw,
    int* __restrict__ list_len, double* __restrict__ imp, double* __restrict__ loadacc,
    int* __restrict__ aidx, float* __restrict__ keyarr, float* __restrict__ warr)
{
  __shared__ float Wl[NE * DIM];
  const int tid = threadIdx.x;
  for (int i = tid; i < NE * DIM; i += 256) {
    int e = i / DIM, d = i - e * DIM;
    Wl[i] = rw[d * NE + e];
  }
  __syncthreads();
  const int wave = tid >> 6, lane = tid & 63;
  double my_imp = 0.0, my_load = 0.0;

  for (int it = 0; it < 8; ++it) {
    const int n = blockIdx.x * 32 + wave * 8 + it;
    const float* xr = x + (size_t)n * DIM;
    float part[NE];
#pragma unroll
    for (int e = 0; e < NE; ++e) part[e] = 0.f;
#pragma unroll
    for (int c = 0; c < DIM / 64; ++c) {
      float xv = xr[c * 64 + lane];
#pragma unroll
      for (int e = 0; e < NE; ++e) part[e] += xv * Wl[e * DIM + c * 64 + lane];
    }
#pragma unroll
    for (int off = 32; off > 0; off >>= 1) {
#pragma unroll
      for (int e = 0; e < NE; ++e) part[e] += __shfl_xor(part[e], off);
    }
    int e0 = 0; float v0 = part[0];
#pragma unroll
    for (int e = 1; e < NE; ++e) if (part[e] > v0) { v0 = part[e]; e0 = e; }
    int e1 = -1; float v1 = -3.4e38f;
#pragma unroll
    for (int e = 0; e < NE; ++e) if (e != e0 && part[e] > v1) { v1 = part[e]; e1 = e; }

    float pexp[NE]; float s = 0.f;
#pragma unroll
    for (int e = 0; e < NE; ++e) { pexp[e] = expf(part[e] - v0); s += pexp[e]; }
    const float inv = 1.0f / s;
    const float pr = inv;
    float w1v = 0.f;
#pragma unroll
    for (int e = 0; e < NE; ++e) if (e == e1) w1v = pexp[e] * inv;

    float myl = 0.f, mypexp = 0.f;
#pragma unroll
    for (int e = 0; e < NE; ++e) if (lane == e) { myl = part[e]; mypexp = pexp[e]; }
    if (lane < NE) {
      my_imp  += (double)(mypexp * inv);
      my_load += (double)(0.5f * erfcf((v1 - myl) * 5.656854249492380f));
    }
    if (lane == 0) {
      int p0 = atomicAdd(&list_len[e0], 1);
      int p1 = atomicAdd(&list_len[e1], 1);
      aidx[e0 * AMAX + p0]   = n * 2;
      keyarr[e0 * AMAX + p0] = (float)(e0 * 4) - pr;
      warr[e0 * AMAX + p0]   = pr;
      aidx[e1 * AMAX + p1]   = n * 2 + 1;
      keyarr[e1 * AMAX + p1] = (float)(e1 * 4) - (pr - 1.0f);
      warr[e1 * AMAX + p1]   = w1v;
    }
  }
  if (lane < NE) {
    unsafeAtomicAdd(&imp[lane], my_imp);
    unsafeAtomicAdd(&loadacc[lane], my_load);
  }
}

// ---------------- capacity keep/compact + scalar outputs -------------------------------
__global__ __launch_bounds__(256) void compact_kernel(
    const int* __restrict__ list_len, const int* __restrict__ aidx,
    const float* __restrict__ keyarr, const float* __restrict__ warr,
    int* __restrict__ dtok, float* __restrict__ dw,
    const double* __restrict__ imp, const double* __restrict__ loadacc,
    float* __restrict__ out_scalars)
{
  __shared__ float sk[6144];
  __shared__ int   sa[6144];
  const int e = blockIdx.x, tid = threadIdx.x;
  const int C = list_len[e];
  if (C <= CAP) {
    for (int t = tid; t < C; t += 256) {
      int a = aidx[e * AMAX + t];
      dtok[e * CAP + t] = a >> 1;
      dw[e * CAP + t]   = warr[e * AMAX + t];
    }
  } else {
    const bool useL = (C <= 6144);
    if (useL) {
      for (int t = tid; t < C; t += 256) { sk[t] = keyarr[e*AMAX+t]; sa[t] = aidx[e*AMAX+t]; }
      __syncthreads();
    }
    for (int t = tid; t < C; t += 256) {
      float kt = keyarr[e*AMAX+t]; int at = aidx[e*AMAX+t];
      int r = 0;
      for (int u = 0; u < C; ++u) {
        float ku = useL ? sk[u] : keyarr[e*AMAX+u];
        int   au = useL ? sa[u] : aidx[e*AMAX+u];
        if (ku < kt || (ku == kt && au < at)) ++r;
      }
      if (r < CAP) { dtok[e*CAP + r] = at >> 1; dw[e*CAP + r] = warr[e*AMAX+t]; }
    }
  }
  if (e == 0 && tid == 0) {
    double mi = 0, ml = 0;
    for (int i = 0; i < NE; ++i) { mi += imp[i]; ml += loadacc[i]; }
    mi /= NE; ml /= NE;
    double vi = 0, vl = 0;
    for (int i = 0; i < NE; ++i) {
      double di = imp[i] - mi;     vi += di * di;
      double dl = loadacc[i] - ml; vl += dl * dl;
    }
    vi /= NE; vl /= NE;
    double li = vi / (mi * mi + 1e-6), ll = vl / (ml * ml + 1e-6);
    out_scalars[0] = (float)(0.5 * (li + ll));
    int drop = 0;
    for (int i = 0; i < NE; ++i) { int c2 = list_len[i]; if (c2 > CAP) drop += c2 - CAP; }
    out_scalars[1] = (float)drop;
    for (int i = 0; i < NE; ++i) out_scalars[2 + i] = (float)list_len[i];
  }
}

// ---------------- gather kept rows into padded bf16 A buffer [E][CAP][DIM] -------------
__global__ __launch_bounds__(256) void gather_kernel(
    const float* __restrict__ x, const int* __restrict__ dtok,
    const int* __restrict__ list_len, __bf16* __restrict__ Ag)
{
  const int row  = blockIdx.x * 4 + (threadIdx.x >> 6);
  const int lane = threadIdx.x & 63;
  const int e = row / CAP, slot = row - e * CAP;
  const int kept = min(list_len[e], CAP);
  __bf16* dst = Ag + (size_t)row * DIM;
  if (slot < kept) {
    const float* srcr = x + (size_t)dtok[e * CAP + slot] * DIM;
#pragma unroll
    for (int c = 0; c < DIM / 128; ++c) {
      float2 v = *(const float2*)(srcr + c * 128 + lane * 2);
      bf16x2 o; o[0] = (__bf16)v.x; o[1] = (__bf16)v.y;
      *(bf16x2*)(dst + c * 128 + lane * 2) = o;
    }
  } else {
    bf16x2 z; z[0] = (__bf16)0.f; z[1] = (__bf16)0.f;
#pragma unroll
    for (int c = 0; c < DIM / 128; ++c) *(bf16x2*)(dst + c * 128 + lane * 2) = z;
  }
}

// ---------------- grouped GEMM: 128x256 tile, depth-2 gl_lds pipeline ------------------
// C[M,N] = A[M,K] * BT[N,K]^T per expert. 4 waves: (wm,wn) = 64-row x 128-col quadrant,
// acc[4][8] per wave (32 MFMA/iter). 3 LDS buffers (A 8KB + B 16KB each), raw s_barrier
// + per-wave vmcnt(6) so iter k+2's loads stay in flight across the barrier.
// e = xcd for both GEMMs (expert weights L2-resident per XCD).
// MODE 0 (FC1): tn = q/tilesM (12 groups). MODE 1 (FC2): split-K=2, pr=q/tilesM,
// tn=pr%3, ks=pr/3; bias only at ks==0; atomic scatter epilogue.
template<int MODE>
__global__ __launch_bounds__(256, 2) void moe_gemm(
    const __bf16* __restrict__ Aall, const __bf16* __restrict__ BTall,
    const float* __restrict__ bias, __bf16* __restrict__ Hout,
    float* __restrict__ Out, const int* __restrict__ dtok, const float* __restrict__ dww,
    const int* __restrict__ list_len, int Kd, int Nd, int tilesM)
{
  const int i_blk = blockIdx.x;
  const int xcd = i_blk & 7, q = i_blk >> 3;
  const int e = xcd;
  const int tm = q % tilesM;
  int tn, ks, kbase, kIters;
  if (MODE == 0) {
    tn = q / tilesM; ks = 0; kbase = 0; kIters = Kd >> 5;
  } else {
    const int pr = q / tilesM;
    tn = pr % 3; ks = pr / 3; kbase = ks * (Kd >> 1); kIters = Kd >> 6;
  }

  const int kept = min(list_len[e], CAP);
  const int mUsed = (kept + 127) >> 7;
  if (tm >= mUsed) return;

  // 3 buffers x (A 4096 elems + B 8192 elems) = 72 KB
  __shared__ __bf16 S[3][12288];

  const int tid = threadIdx.x, lane = tid & 63, wave = tid >> 6;
  const int wm = wave & 1, wn = wave >> 1;
  const int m0 = tm * 128, n0 = tn * 256;

  const __bf16* Ae = Aall + (size_t)e * CAP * Kd + kbase;
  const __bf16* Be = BTall + (size_t)e * Nd * Kd + kbase;

  const int lr = lane & 15, lc = (lane >> 4) * 8;
  // wave issues A groups {2w,2w+1} (16 rows each), B groups {4w..4w+3}
  const __bf16* gA[2]; const __bf16* gB[4];
  int sAo[2], sBo[4];
#pragma unroll
  for (int a = 0; a < 2; ++a) {
    const int g = wave * 2 + a;
    gA[a] = Ae + (size_t)(m0 + g * 16 + lr) * Kd + lc;
    sAo[a] = g * 512;
  }
#pragma unroll
  for (int b = 0; b < 4; ++b) {
    const int h = wave * 4 + b;
    gB[b] = Be + (size_t)(n0 + h * 16 + lr) * Kd + lc;
    sBo[b] = 4096 + h * 512;
  }

  floatx4 acc[4][8];
#pragma unroll
  for (int i = 0; i < 4; ++i)
#pragma unroll
    for (int j = 0; j < 8; ++j) acc[i][j] = (floatx4)0.f;

#define ISSUE(J, Bf)                                           \
  do {                                                         \
    const int _off = (J) * 32;                                 \
    gl_lds16(gA[0] + _off, &S[(Bf)][sAo[0]]);                  \
    gl_lds16(gA[1] + _off, &S[(Bf)][sAo[1]]);                  \
    gl_lds16(gB[0] + _off, &S[(Bf)][sBo[0]]);                  \
    gl_lds16(gB[1] + _off, &S[(Bf)][sBo[1]]);                  \
    gl_lds16(gB[2] + _off, &S[(Bf)][sBo[2]]);                  \
    gl_lds16(gB[3] + _off, &S[(Bf)][sBo[3]]);                  \
  } while (0)

  ISSUE(0, 0);
  ISSUE(1, 1);
  int cur = 0;
  for (int kt = 0; kt < kIters; ++kt) {
    // drain this iter's 6 loads (issued 2 iters ago); keep next iter's 6 in flight
    if (kt < kIters - 1) __builtin_amdgcn_s_waitcnt(0x0F76);   // vmcnt(6)
    else                 __builtin_amdgcn_s_waitcnt(0x0F70);   // vmcnt(0)
    asm volatile("" ::: "memory");
    __builtin_amdgcn_s_barrier();
    asm volatile("" ::: "memory");

    bf16x8 af[4], bfr[8];
#pragma unroll
    for (int i = 0; i < 4; ++i)
      af[i]  = *(const bf16x8*)(&S[cur][((wm * 4 + i) * 64 + lane) * 8]);
#pragma unroll
    for (int j = 0; j < 8; ++j)
      bfr[j] = *(const bf16x8*)(&S[cur][4096 * 2 + ((wn * 8 + j) * 64 + lane) * 8 - 4096]);

    if (kt + 2 < kIters) {
      int nb = cur + 2; if (nb >= 3) nb -= 3;
      ISSUE(kt + 2, nb);
    }

#pragma unroll
    for (int i = 0; i < 4; ++i)
#pragma unroll
      for (int j = 0; j < 8; ++j)
        acc[i][j] = __builtin_amdgcn_mfma_f32_16x16x32_bf16(af[i], bfr[j], acc[i][j], 0, 0, 0);

    cur = (cur == 2) ? 0 : cur + 1;
  }
#undef ISSUE

  const int quad = lane >> 4, lcol = lane & 15;
  float bcol[8];
#pragma unroll
  for (int j = 0; j < 8; ++j)
    bcol[j] = (MODE == 1 && ks == 1) ? 0.f : bias[e * Nd + n0 + wn * 128 + j * 16 + lcol];

  if (MODE == 0) {
#pragma unroll
    for (int i = 0; i < 4; ++i) {
#pragma unroll
      for (int r = 0; r < 4; ++r) {
        const int row = m0 + wm * 64 + i * 16 + quad * 4 + r;  // C/D: row=(l>>4)*4+reg, col=l&15
        __bf16* hrow = Hout + ((size_t)(e * CAP + row)) * Nd;
#pragma unroll
        for (int j = 0; j < 8; ++j) {
          float v = acc[i][j][r] + bcol[j];
          hrow[n0 + wn * 128 + j * 16 + lcol] = (__bf16)gelu_exact(v);
        }
      }
    }
  } else {
#pragma unroll
    for (int i = 0; i < 4; ++i) {
#pragma unroll
      for (int r = 0; r < 4; ++r) {
        const int row = m0 + wm * 64 + i * 16 + quad * 4 + r;
        const float w = dww[e * CAP + row];
        if (w != 0.0f) {
          const int tok = dtok[e * CAP + row];
          float* orow = Out + (size_t)tok * DIM;
#pragma unroll
          for (int j = 0; j < 8; ++j) {
            float v = w * (acc[i][j][r] + bcol[j]);
            unsafeAtomicAdd(&orow[n0 + wn * 128 + j * 16 + lcol], v);
          }
        }
      }
    }
  }
}

extern "C" void kernel_launch(void* const* d_in, const int* in_sizes, int n_in,
                              void* d_out, int out_size, void* d_ws, size_t ws_size,
                              hipStream_t stream) {
  (void)in_sizes; (void)n_in; (void)out_size; (void)ws_size;
  const float* x  = (const float*)d_in[0];
  const float* rw = (const float*)d_in[1];
  const float* w1 = (const float*)d_in[2];
  const float* b1 = (const float*)d_in[3];
  const float* w2 = (const float*)d_in[4];
  const float* b2 = (const float*)d_in[5];
  float* out = (float*)d_out;
  char* ws = (char*)d_ws;

  int*    list_len = (int*)(ws + 0);
  double* imp      = (double*)(ws + 64);
  double* loadacc  = (double*)(ws + 128);
  int*    dtok     = (int*)(ws + 256);
  float*  dw       = (float*)(ws + 256 + 81920);
  int*    aidx     = (int*)(ws + 164096);
  float*  keyarr   = (float*)(ws + 164096 + 524288);
  float*  warr     = (float*)(ws + 164096 + 1048576);
  __bf16* W1T      = (__bf16*)(ws + 2097152);
  __bf16* W2T      = (__bf16*)(ws + 2097152 + 37748736);
  __bf16* Ag       = (__bf16*)(ws + 2097152 + 2 * 37748736);
  __bf16* hbuf     = (__bf16*)(ws + 2097152 + 2 * 37748736 + 31457280);

  hipMemsetAsync(d_out, 0, (size_t)NTOK * DIM * sizeof(float), stream);
  hipMemsetAsync(ws, 0, 164096, stream);

  transpose_conv2<<<dim3(576, 8, 2), 256, 0, stream>>>(w1, w2, W1T, W2T);
  router_kernel<<<NTOK / 32, 256, 0, stream>>>(x, rw, list_len, imp, loadacc, aidx, keyarr, warr);
  compact_kernel<<<NE, 256, 0, stream>>>(list_len, aidx, keyarr, warr, dtok, dw, imp, loadacc,
                                         out + (size_t)NTOK * DIM);
  gather_kernel<<<(NE * CAP) / 4, 256, 0, stream>>>(x, dtok, list_len, Ag);
  // FC1: 8 XCD x (20 tm x 12 tn) = 1920 blocks
  moe_gemm<0><<<NE * 20 * (HDIM / 256), 256, 0, stream>>>(
      Ag, W1T, b1, hbuf, nullptr, nullptr, nullptr, list_len, DIM, HDIM, 20);
  // FC2: 8 XCD x (20 tm x 3 tn x 2 ksplit) = 960 blocks
  moe_gemm<1><<<NE * 20 * (DIM / 256) * 2, 256, 0, stream>>>(
      hbuf, W2T, b2, nullptr, out, dtok, dw, list_len, HDIM, DIM, 20);
}

// Round 5
// 579.217 us; speedup vs baseline: 1.5163x; 1.2895x over previous
//
#include <hip/hip_runtime.h>
#include <hip/hip_bf16.h>
#include <math.h>

#define NTOK 8192
#define DIM  768
#define HDIM 3072
#define NE   8
#define CAP  2560
#define AMAX 16384

typedef __bf16 bf16x8  __attribute__((ext_vector_type(8)));
typedef __bf16 bf16x2  __attribute__((ext_vector_type(2)));
typedef float  floatx4 __attribute__((ext_vector_type(4)));

typedef unsigned int u32_g __attribute__((address_space(1)));
typedef unsigned int u32_l __attribute__((address_space(3)));

__device__ __forceinline__ void gl_lds16(const void* g, void* l) {
  // 16B per lane, LDS dest = wave-uniform base + lane*16
  __builtin_amdgcn_global_load_lds((const u32_g*)g, (u32_l*)l, 16, 0, 0);
}

// gelu exact via A&S 7.1.26 erf poly (|err| < 1.5e-7)
__device__ __forceinline__ float gelu_exact(float v) {
  float z = fabsf(v) * 0.7071067811865475f;
  float t = __builtin_amdgcn_rcpf(1.0f + 0.3275911f * z);
  float p = ((((1.061405429f * t - 1.453152027f) * t + 1.421413741f) * t
              - 0.284496736f) * t + 0.254829592f) * t;
  float e = 1.0f - p * __expf(-z * z);
  e = copysignf(e, v);
  return 0.5f * v * (1.0f + e);
}

// ---------------- fused weight transpose + fp32->bf16: [E][K][N] -> [E][N][K] ----------
__global__ __launch_bounds__(256) void transpose_conv2(
    const float* __restrict__ w1, const float* __restrict__ w2,
    __bf16* __restrict__ o1, __bf16* __restrict__ o2)
{
  const int which = blockIdx.z;
  const float* src = which ? w2 : w1;
  __bf16* dst = which ? o2 : o1;
  const int Kd = which ? HDIM : DIM;
  const int Nd = which ? DIM : HDIM;
  const int e = blockIdx.y;
  const int tilesK = Kd >> 6;
  const int bk = blockIdx.x % tilesK, bn = blockIdx.x / tilesK;
  __shared__ float T[64][65];
  const float* se = src + (size_t)e * Kd * Nd;
  const int k0 = bk * 64, n0 = bn * 64;
  const int tid = threadIdx.x;
#pragma unroll
  for (int it = 0; it < 16; ++it) {
    int flat = tid + it * 256;
    int kk = flat >> 6, nn = flat & 63;
    T[kk][nn] = se[(size_t)(k0 + kk) * Nd + n0 + nn];
  }
  __syncthreads();
  const int n = tid >> 2, kg = tid & 3;
  bf16x8 v0, v1;
#pragma unroll
  for (int q = 0; q < 8; ++q) v0[q] = (__bf16)T[kg * 16 + q][n];
#pragma unroll
  for (int q = 0; q < 8; ++q) v1[q] = (__bf16)T[kg * 16 + 8 + q][n];
  __bf16* de = dst + (size_t)e * Nd * Kd + (size_t)(n0 + n) * Kd + k0 + kg * 16;
  *(bf16x8*)(de) = v0;
  *(bf16x8*)(de + 8) = v1;
}

// ---------------- router: block-aggregated dispatch (1 global atomic per expert/block) --
__global__ __launch_bounds__(256) void router_kernel(
    const float* __restrict__ x, const float* __restrict__ rw,
    int* __restrict__ list_len, double* __restrict__ imp, double* __restrict__ loadacc,
    int* __restrict__ aidx, float* __restrict__ keyarr, float* __restrict__ warr)
{
  __shared__ float Wl[NE * DIM];
  __shared__ int   lcount[NE], lbase[NE];
  __shared__ int   s_e[32][2], s_pos[32][2];
  __shared__ float s_key[32][2], s_w[32][2];
  const int tid = threadIdx.x;
  for (int i = tid; i < NE * DIM; i += 256) {
    int e = i / DIM, d = i - e * DIM;
    Wl[i] = rw[d * NE + e];
  }
  if (tid < NE) lcount[tid] = 0;
  __syncthreads();
  const int wave = tid >> 6, lane = tid & 63;
  double my_imp = 0.0, my_load = 0.0;

  for (int it = 0; it < 8; ++it) {
    const int t = wave * 8 + it;               // block-local token
    const int n = blockIdx.x * 32 + t;
    const float* xr = x + (size_t)n * DIM;
    float part[NE];
#pragma unroll
    for (int e = 0; e < NE; ++e) part[e] = 0.f;
#pragma unroll
    for (int c = 0; c < DIM / 64; ++c) {
      float xv = xr[c * 64 + lane];
#pragma unroll
      for (int e = 0; e < NE; ++e) part[e] += xv * Wl[e * DIM + c * 64 + lane];
    }
#pragma unroll
    for (int off = 32; off > 0; off >>= 1) {
#pragma unroll
      for (int e = 0; e < NE; ++e) part[e] += __shfl_xor(part[e], off);
    }
    // top-2, ties -> lower index (lax.top_k semantics)
    int e0 = 0; float v0 = part[0];
#pragma unroll
    for (int e = 1; e < NE; ++e) if (part[e] > v0) { v0 = part[e]; e0 = e; }
    int e1 = -1; float v1 = -3.4e38f;
#pragma unroll
    for (int e = 0; e < NE; ++e) if (e != e0 && part[e] > v1) { v1 = part[e]; e1 = e; }

    float pexp[NE]; float s = 0.f;
#pragma unroll
    for (int e = 0; e < NE; ++e) { pexp[e] = expf(part[e] - v0); s += pexp[e]; }
    const float inv = 1.0f / s;
    const float pr = inv;               // top-1 prob = priority
    float w1v = 0.f;
#pragma unroll
    for (int e = 0; e < NE; ++e) if (e == e1) w1v = pexp[e] * inv;

    // per-lane-expert double accumulation: lane e accumulates expert e
    float myl = 0.f, mypexp = 0.f;
#pragma unroll
    for (int e = 0; e < NE; ++e) if (lane == e) { myl = part[e]; mypexp = pexp[e]; }
    if (lane < NE) {
      my_imp  += (double)(mypexp * inv);
      // 1 - Phi((thr - logit)/NOISE_STD) = 0.5*erfc((thr-logit)/(0.125*sqrt(2)))
      my_load += (double)(0.5f * erfcf((v1 - myl) * 5.656854249492380f));
    }
    if (lane == 0) {
      int p0 = atomicAdd(&lcount[e0], 1);      // LDS atomic (cheap)
      int p1 = atomicAdd(&lcount[e1], 1);
      s_e[t][0] = e0; s_pos[t][0] = p0;
      s_key[t][0] = (float)(e0 * 4) - pr;      // e*(K+2) - score, fp32 like ref
      s_w[t][0] = pr;
      s_e[t][1] = e1; s_pos[t][1] = p1;
      s_key[t][1] = (float)(e1 * 4) - (pr - 1.0f);
      s_w[t][1] = w1v;
    }
  }
  __syncthreads();
  if (tid < NE) lbase[tid] = atomicAdd(&list_len[tid], lcount[tid]);  // 8 global atomics/block
  __syncthreads();
  if (tid < 64) {
    const int t = tid >> 1, sl = tid & 1;
    const int e = s_e[t][sl];
    const int gp = lbase[e] + s_pos[t][sl];
    const int n = blockIdx.x * 32 + t;
    aidx[e * AMAX + gp]   = n * 2 + sl;
    keyarr[e * AMAX + gp] = s_key[t][sl];
    warr[e * AMAX + gp]   = s_w[t][sl];
  }
  if (lane < NE) {
    unsafeAtomicAdd(&imp[lane], my_imp);
    unsafeAtomicAdd(&loadacc[lane], my_load);
  }
}

// ---------------- capacity keep/compact + scalar outputs -------------------------------
__global__ __launch_bounds__(256) void compact_kernel(
    const int* __restrict__ list_len, const int* __restrict__ aidx,
    const float* __restrict__ keyarr, const float* __restrict__ warr,
    int* __restrict__ dtok, float* __restrict__ dw,
    const double* __restrict__ imp, const double* __restrict__ loadacc,
    float* __restrict__ out_scalars)
{
  __shared__ float sk[6144];
  __shared__ int   sa[6144];
  const int e = blockIdx.x, tid = threadIdx.x;
  const int C = list_len[e];
  if (C <= CAP) {
    for (int t = tid; t < C; t += 256) {
      int a = aidx[e * AMAX + t];
      dtok[e * CAP + t] = a >> 1;
      dw[e * CAP + t]   = warr[e * AMAX + t];
    }
  } else {
    const bool useL = (C <= 6144);
    if (useL) {
      for (int t = tid; t < C; t += 256) { sk[t] = keyarr[e*AMAX+t]; sa[t] = aidx[e*AMAX+t]; }
      __syncthreads();
    }
    for (int t = tid; t < C; t += 256) {
      float kt = keyarr[e*AMAX+t]; int at = aidx[e*AMAX+t];
      int r = 0;
      for (int u = 0; u < C; ++u) {
        float ku = useL ? sk[u] : keyarr[e*AMAX+u];
        int   au = useL ? sa[u] : aidx[e*AMAX+u];
        if (ku < kt || (ku == kt && au < at)) ++r;
      }
      if (r < CAP) { dtok[e*CAP + r] = at >> 1; dw[e*CAP + r] = warr[e*AMAX+t]; }
    }
  }
  if (e == 0 && tid == 0) {
    double mi = 0, ml = 0;
    for (int i = 0; i < NE; ++i) { mi += imp[i]; ml += loadacc[i]; }
    mi /= NE; ml /= NE;
    double vi = 0, vl = 0;
    for (int i = 0; i < NE; ++i) {
      double di = imp[i] - mi;     vi += di * di;
      double dl = loadacc[i] - ml; vl += dl * dl;
    }
    vi /= NE; vl /= NE;
    double li = vi / (mi * mi + 1e-6), ll = vl / (ml * ml + 1e-6);
    out_scalars[0] = (float)(0.5 * (li + ll));
    int drop = 0;
    for (int i = 0; i < NE; ++i) { int c2 = list_len[i]; if (c2 > CAP) drop += c2 - CAP; }
    out_scalars[1] = (float)drop;
    for (int i = 0; i < NE; ++i) out_scalars[2 + i] = (float)list_len[i];
  }
}

// ---------------- gather kept rows into padded bf16 A buffer [E][CAP][DIM] -------------
__global__ __launch_bounds__(256) void gather_kernel(
    const float* __restrict__ x, const int* __restrict__ dtok,
    const int* __restrict__ list_len, __bf16* __restrict__ Ag)
{
  const int row  = blockIdx.x * 4 + (threadIdx.x >> 6);
  const int lane = threadIdx.x & 63;
  const int e = row / CAP, slot = row - e * CAP;
  const int kept = min(list_len[e], CAP);
  __bf16* dst = Ag + (size_t)row * DIM;
  if (slot < kept) {
    const float* srcr = x + (size_t)dtok[e * CAP + slot] * DIM;
#pragma unroll
    for (int c = 0; c < DIM / 128; ++c) {
      float2 v = *(const float2*)(srcr + c * 128 + lane * 2);
      bf16x2 o; o[0] = (__bf16)v.x; o[1] = (__bf16)v.y;
      *(bf16x2*)(dst + c * 128 + lane * 2) = o;
    }
  } else {
    bf16x2 z; z[0] = (__bf16)0.f; z[1] = (__bf16)0.f;
#pragma unroll
    for (int c = 0; c < DIM / 128; ++c) *(bf16x2*)(dst + c * 128 + lane * 2) = z;
  }
}

// ---------------- grouped GEMM: 128x256 tile, depth-2 gl_lds pipeline ------------------
// C[M,N] = A[M,K] * BT[N,K]^T per expert. 4 waves: (wm,wn) = 64-row x 128-col quadrant,
// acc[4][8] per wave (32 MFMA/iter). 3 LDS buffers (A 8KB + B 16KB each), raw s_barrier
// + per-wave vmcnt(6) so iter k+2's loads stay in flight across the barrier.
// e = xcd for both GEMMs (expert weights L2-resident per XCD).
// MODE 0 (FC1): tn = q/tilesM (12 groups). MODE 1 (FC2): split-K=2, pr=q/tilesM,
// tn=pr%3, ks=pr/3; bias only at ks==0; atomic scatter epilogue.
template<int MODE>
__global__ __launch_bounds__(256, 2) void moe_gemm(
    const __bf16* __restrict__ Aall, const __bf16* __restrict__ BTall,
    const float* __restrict__ bias, __bf16* __restrict__ Hout,
    float* __restrict__ Out, const int* __restrict__ dtok, const float* __restrict__ dww,
    const int* __restrict__ list_len, int Kd, int Nd, int tilesM)
{
  const int i_blk = blockIdx.x;
  const int xcd = i_blk & 7, q = i_blk >> 3;
  const int e = xcd;
  const int tm = q % tilesM;
  int tn, ks, kbase, kIters;
  if (MODE == 0) {
    tn = q / tilesM; ks = 0; kbase = 0; kIters = Kd >> 5;
  } else {
    const int pr = q / tilesM;
    tn = pr % 3; ks = pr / 3; kbase = ks * (Kd >> 1); kIters = Kd >> 6;
  }

  const int kept = min(list_len[e], CAP);
  const int mUsed = (kept + 127) >> 7;
  if (tm >= mUsed) return;

  // 3 buffers x (A 4096 elems + B 8192 elems) = 72 KB
  __shared__ __bf16 S[3][12288];

  const int tid = threadIdx.x, lane = tid & 63, wave = tid >> 6;
  const int wm = wave & 1, wn = wave >> 1;
  const int m0 = tm * 128, n0 = tn * 256;

  const __bf16* Ae = Aall + (size_t)e * CAP * Kd + kbase;
  const __bf16* Be = BTall + (size_t)e * Nd * Kd + kbase;

  const int lr = lane & 15, lc = (lane >> 4) * 8;
  const __bf16* gA[2]; const __bf16* gB[4];
  int sAo[2], sBo[4];
#pragma unroll
  for (int a = 0; a < 2; ++a) {
    const int g = wave * 2 + a;
    gA[a] = Ae + (size_t)(m0 + g * 16 + lr) * Kd + lc;
    sAo[a] = g * 512;
  }
#pragma unroll
  for (int b = 0; b < 4; ++b) {
    const int h = wave * 4 + b;
    gB[b] = Be + (size_t)(n0 + h * 16 + lr) * Kd + lc;
    sBo[b] = 4096 + h * 512;
  }

  floatx4 acc[4][8];
#pragma unroll
  for (int i = 0; i < 4; ++i)
#pragma unroll
    for (int j = 0; j < 8; ++j) acc[i][j] = (floatx4)0.f;

#define ISSUE(J, Bf)                                           \
  do {                                                         \
    const int _off = (J) * 32;                                 \
    gl_lds16(gA[0] + _off, &S[(Bf)][sAo[0]]);                  \
    gl_lds16(gA[1] + _off, &S[(Bf)][sAo[1]]);                  \
    gl_lds16(gB[0] + _off, &S[(Bf)][sBo[0]]);                  \
    gl_lds16(gB[1] + _off, &S[(Bf)][sBo[1]]);                  \
    gl_lds16(gB[2] + _off, &S[(Bf)][sBo[2]]);                  \
    gl_lds16(gB[3] + _off, &S[(Bf)][sBo[3]]);                  \
  } while (0)

  ISSUE(0, 0);
  ISSUE(1, 1);
  int cur = 0;
  for (int kt = 0; kt < kIters; ++kt) {
    if (kt < kIters - 1) __builtin_amdgcn_s_waitcnt(0x0F76);   // vmcnt(6)
    else                 __builtin_amdgcn_s_waitcnt(0x0F70);   // vmcnt(0)
    asm volatile("" ::: "memory");
    __builtin_amdgcn_s_barrier();
    asm volatile("" ::: "memory");

    bf16x8 af[4], bfr[8];
#pragma unroll
    for (int i = 0; i < 4; ++i)
      af[i]  = *(const bf16x8*)(&S[cur][((wm * 4 + i) * 64 + lane) * 8]);
#pragma unroll
    for (int j = 0; j < 8; ++j)
      bfr[j] = *(const bf16x8*)(&S[cur][4096 + ((wn * 8 + j) * 64 + lane) * 8]);

    if (kt + 2 < kIters) {
      int nb = cur + 2; if (nb >= 3) nb -= 3;
      ISSUE(kt + 2, nb);
    }

#pragma unroll
    for (int i = 0; i < 4; ++i)
#pragma unroll
      for (int j = 0; j < 8; ++j)
        acc[i][j] = __builtin_amdgcn_mfma_f32_16x16x32_bf16(af[i], bfr[j], acc[i][j], 0, 0, 0);

    cur = (cur == 2) ? 0 : cur + 1;
  }
#undef ISSUE

  const int quad = lane >> 4, lcol = lane & 15;
  float bcol[8];
#pragma unroll
  for (int j = 0; j < 8; ++j)
    bcol[j] = (MODE == 1 && ks == 1) ? 0.f : bias[e * Nd + n0 + wn * 128 + j * 16 + lcol];

  if (MODE == 0) {
#pragma unroll
    for (int i = 0; i < 4; ++i) {
#pragma unroll
      for (int r = 0; r < 4; ++r) {
        const int row = m0 + wm * 64 + i * 16 + quad * 4 + r;  // C/D: row=(l>>4)*4+reg, col=l&15
        __bf16* hrow = Hout + ((size_t)(e * CAP + row)) * Nd;
#pragma unroll
        for (int j = 0; j < 8; ++j) {
          float v = acc[i][j][r] + bcol[j];
          hrow[n0 + wn * 128 + j * 16 + lcol] = (__bf16)gelu_exact(v);
        }
      }
    }
  } else {
#pragma unroll
    for (int i = 0; i < 4; ++i) {
#pragma unroll
      for (int r = 0; r < 4; ++r) {
        const int row = m0 + wm * 64 + i * 16 + quad * 4 + r;
        const float w = dww[e * CAP + row];
        if (w != 0.0f) {
          const int tok = dtok[e * CAP + row];
          float* orow = Out + (size_t)tok * DIM;
#pragma unroll
          for (int j = 0; j < 8; ++j) {
            float v = w * (acc[i][j][r] + bcol[j]);
            unsafeAtomicAdd(&orow[n0 + wn * 128 + j * 16 + lcol], v);
          }
        }
      }
    }
  }
}

extern "C" void kernel_launch(void* const* d_in, const int* in_sizes, int n_in,
                              void* d_out, int out_size, void* d_ws, size_t ws_size,
                              hipStream_t stream) {
  (void)in_sizes; (void)n_in; (void)out_size; (void)ws_size;
  const float* x  = (const float*)d_in[0];
  const float* rw = (const float*)d_in[1];
  const float* w1 = (const float*)d_in[2];
  const float* b1 = (const float*)d_in[3];
  const float* w2 = (const float*)d_in[4];
  const float* b2 = (const float*)d_in[5];
  float* out = (float*)d_out;
  char* ws = (char*)d_ws;

  int*    list_len = (int*)(ws + 0);
  double* imp      = (double*)(ws + 64);
  double* loadacc  = (double*)(ws + 128);
  int*    dtok     = (int*)(ws + 256);
  float*  dw       = (float*)(ws + 256 + 81920);
  int*    aidx     = (int*)(ws + 164096);
  float*  keyarr   = (float*)(ws + 164096 + 524288);
  float*  warr     = (float*)(ws + 164096 + 1048576);
  __bf16* W1T      = (__bf16*)(ws + 2097152);
  __bf16* W2T      = (__bf16*)(ws + 2097152 + 37748736);
  __bf16* Ag       = (__bf16*)(ws + 2097152 + 2 * 37748736);
  __bf16* hbuf     = (__bf16*)(ws + 2097152 + 2 * 37748736 + 31457280);

  hipMemsetAsync(d_out, 0, (size_t)NTOK * DIM * sizeof(float), stream);
  hipMemsetAsync(ws, 0, 164096, stream);

  transpose_conv2<<<dim3(576, 8, 2), 256, 0, stream>>>(w1, w2, W1T, W2T);
  router_kernel<<<NTOK / 32, 256, 0, stream>>>(x, rw, list_len, imp, loadacc, aidx, keyarr, warr);
  compact_kernel<<<NE, 256, 0, stream>>>(list_len, aidx, keyarr, warr, dtok, dw, imp, loadacc,
                                         out + (size_t)NTOK * DIM);
  gather_kernel<<<(NE * CAP) / 4, 256, 0, stream>>>(x, dtok, list_len, Ag);
  // FC1: 8 XCD x (20 tm x 12 tn) = 1920 blocks
  moe_gemm<0><<<NE * 20 * (HDIM / 256), 256, 0, stream>>>(
      Ag, W1T, b1, hbuf, nullptr, nullptr, nullptr, list_len, DIM, HDIM, 20);
  // FC2: 8 XCD x (20 tm x 3 tn x 2 ksplit) = 960 blocks
  moe_gemm<1><<<NE * 20 * (DIM / 256) * 2, 256, 0, stream>>>(
      hbuf, W2T, b2, nullptr, out, dtok, dw, list_len, HDIM, DIM, 20);
}